// Round 1
// baseline (1539.733 us; speedup 1.0000x reference)
//
#include <hip/hip_runtime.h>

#define E_N 100000
#define NV_N 50000
#define NG_N 2000

typedef short s8v __attribute__((ext_vector_type(8)));
typedef unsigned short u16x8 __attribute__((ext_vector_type(8)));
typedef float f32x4 __attribute__((ext_vector_type(4)));

__device__ __forceinline__ float bf2f(unsigned short u) {
  return __uint_as_float(((unsigned int)u) << 16);
}
__device__ __forceinline__ unsigned short f2bf(float f) {
  unsigned int u = __float_as_uint(f);
  u = u + 0x7fffu + ((u >> 16) & 1u);   // RNE
  return (unsigned short)(u >> 16);
}

// ---------------- precompute kernels ----------------

// tabs layout: [4][256][1024] bf16. tb0: W1a rows0-7 + b1a; tb1: W1a rows8-15;
// tb2: W2a rows0-7 + b2a; tb3: W2a rows8-15.  (MSB-first bit unpack)
__global__ void k_tables(const float* __restrict__ W1a, const float* __restrict__ b1a,
                         const float* __restrict__ W2a, const float* __restrict__ b2a,
                         unsigned short* __restrict__ tabs) {
  int tid = blockIdx.x * 256 + threadIdx.x;            // < 4*256*1024
  int tb = tid >> 18, v = (tid >> 10) & 255, k = tid & 1023;
  const float* W = (tb < 2) ? W1a : W2a;
  int rbase = (tb & 1) ? 8 : 0;
  float s = 0.f;
  if ((tb & 1) == 0) s = (tb < 2) ? b1a[k] : b2a[k];
  #pragma unroll
  for (int j = 0; j < 8; ++j)
    if ((v >> (7 - j)) & 1) s += W[(rbase + j) * 1024 + k];
  tabs[tid] = f2bf(s);
}

// dst[n*K+k] = bf16(src[k*N+n]) ; K,N multiples of 32
__global__ void k_transpose(const float* __restrict__ src, unsigned short* __restrict__ dst,
                            int K, int N) {
  __shared__ float tile[32][33];
  int ntx = N >> 5;
  int tk = blockIdx.x / ntx, tn = blockIdx.x - tk * ntx;
  int k0 = tk * 32, n0 = tn * 32;
  int lx = threadIdx.x & 31, ly = threadIdx.x >> 5;
  #pragma unroll
  for (int yy = ly; yy < 32; yy += 8)
    tile[yy][lx] = src[(k0 + yy) * N + (n0 + lx)];
  __syncthreads();
  #pragma unroll
  for (int yy = ly; yy < 32; yy += 8)
    dst[(n0 + yy) * K + (k0 + lx)] = f2bf(tile[lx][yy]);
}

__global__ void k_count(const int* __restrict__ ei, int* __restrict__ cnt) {
  int e = blockIdx.x * 256 + threadIdx.x;
  if (e < E_N) atomicAdd(&cnt[ei[E_N + e]], 1);
}

// ---------------- fused edge NNConv kernel ----------------
// Per WG: 128 edges. GEMM theta = hidden @ W^T(bf16) via MFMA, fold x_src
// contraction into registers, scatter msg to agg with global atomics.
template<int NCOLS, int FOUT>
__global__ void __launch_bounds__(512, 2)
k_edge(const float* __restrict__ xsrc, const int* __restrict__ ei,
       const int* __restrict__ eap,
       const unsigned short* __restrict__ tab0,
       const unsigned short* __restrict__ tab1,
       const unsigned short* __restrict__ WT,     // [NCOLS][1024] bf16 (pre-transposed)
       const float* __restrict__ bvec,            // theta bias [1024*? ] indexed i*FOUT+o
       float* __restrict__ agg)                   // [NV][FOUT] fp32, pre-zeroed
{
  constexpr int NOS = FOUT / 16;   // o-slots per lane (2 or 4)
  constexpr int IPW = 64 / FOUT;   // i values per 64-col wave slice (2 or 1)

  __shared__ unsigned short sHid[128 * 256];       // 64KB  (K-quarter, swizzled)
  __shared__ unsigned short sB[2][256 * 32];       // 32KB  (double-buffered B tile)
  __shared__ float sX[128 * 32];                   // 16KB
  __shared__ float sMsg[128 * FOUT];
  __shared__ int sSrc[128];
  __shared__ int sDst[128];
  __shared__ unsigned char sB0[128], sB1[128];

  const int t = threadIdx.x;
  const int l = t & 63;
  const int wid = t >> 6;
  const int wr = wid >> 2;          // 0..1  (row half)
  const int wc = wid & 3;           // 0..3  (col quarter)
  const int lg = l >> 4;            // lane group 0..3
  const int ll = l & 15;
  const int e0 = blockIdx.x * 128;

  if (t < 128) {
    int e = e0 + t;
    if (e < E_N) {
      sSrc[t] = ei[e];
      sDst[t] = ei[E_N + e];
      sB0[t] = (unsigned char)(eap[2 * e] & 255);
      sB1[t] = (unsigned char)(eap[2 * e + 1] & 255);
    } else { sSrc[t] = 0; sDst[t] = -1; sB0[t] = 0; sB1[t] = 0; }
  }
  for (int j = t; j < 128 * FOUT; j += 512) sMsg[j] = 0.f;
  __syncthreads();

  // stage x_src rows (fp32)
  for (int j = t; j < 128 * 32; j += 512) {
    int m = j >> 5, i = j & 31;
    float v = 0.f;
    if (e0 + m < E_N) v = xsrc[sSrc[m] * 32 + i];
    sX[j] = v;
  }
  __syncthreads();

  float msgr[4][4][NOS] = {};

  for (int q = 0; q < 4; ++q) {
    __syncthreads();   // WAR vs previous quarter's A reads
    // build hidden quarter: relu(P0[b0]+P1[b1]) -> bf16, k-block XOR swizzle (m&7)
    #pragma unroll
    for (int j = 0; j < 8; ++j) {
      int s = t + j * 512;              // 0..4095
      int m = s >> 5, b = s & 31;
      int kg = q * 256 + b * 8;
      u16x8 p0 = *(const u16x8*)&tab0[sB0[m] * 1024 + kg];
      u16x8 p1 = *(const u16x8*)&tab1[sB1[m] * 1024 + kg];
      u16x8 hv;
      #pragma unroll
      for (int u = 0; u < 8; ++u) {
        float f = bf2f(p0[u]) + bf2f(p1[u]);
        hv[u] = f2bf(fmaxf(f, 0.f));
      }
      *(u16x8*)&sHid[m * 256 + 8 * (b ^ (m & 7))] = hv;
    }
    __syncthreads();

    for (int nc = 0; nc < NCOLS / 256; ++nc) {
      // per-lane x values for this column chunk
      float xsr[4][4][IPW];
      #pragma unroll
      for (int mf = 0; mf < 4; ++mf)
        #pragma unroll
        for (int r = 0; r < 4; ++r) {
          int row = wr * 64 + mf * 16 + (lg << 2) + r;
          if constexpr (FOUT == 32) {
            int ib = nc * 8 + wc * 2;
            xsr[mf][r][0] = sX[row * 32 + ib];
            xsr[mf][r][1] = sX[row * 32 + ib + 1];
          } else {
            xsr[mf][r][0] = sX[row * 32 + nc * 4 + wc];
          }
        }

      f32x4 acc[4][4];
      #pragma unroll
      for (int mf = 0; mf < 4; ++mf)
        #pragma unroll
        for (int nf = 0; nf < 4; ++nf)
          acc[mf][nf] = (f32x4){0.f, 0.f, 0.f, 0.f};

      u16x8 ld[2];
      {
        int kb = q * 256;
        #pragma unroll
        for (int j = 0; j < 2; ++j) {
          int sl = t + j * 512, n = sl >> 2, bs = sl & 3;
          ld[j] = *(const u16x8*)&WT[(nc * 256 + n) * 1024 + kb + 8 * (bs ^ (n & 3))];
        }
      }
      for (int s8 = 0; s8 < 8; ++s8) {
        const int cur = s8 & 1;
        #pragma unroll
        for (int j = 0; j < 2; ++j) {
          int sl = t + j * 512, n = sl >> 2, bs = sl & 3;
          *(u16x8*)&sB[cur][n * 32 + 8 * bs] = ld[j];
        }
        __syncthreads();
        if (s8 < 7) {   // issue next-stage loads early (latency hides under MFMA)
          int kb = q * 256 + (s8 + 1) * 32;
          #pragma unroll
          for (int j = 0; j < 2; ++j) {
            int sl = t + j * 512, n = sl >> 2, bs = sl & 3;
            ld[j] = *(const u16x8*)&WT[(nc * 256 + n) * 1024 + kb + 8 * (bs ^ (n & 3))];
          }
        }
        const int kkl = s8 * 32;
        s8v av[4], bv[4];
        #pragma unroll
        for (int mf = 0; mf < 4; ++mf) {
          int m = wr * 64 + mf * 16 + ll;
          int blk = (kkl >> 3) + lg;
          av[mf] = *(const s8v*)&sHid[m * 256 + 8 * (blk ^ (m & 7))];
        }
        #pragma unroll
        for (int nf = 0; nf < 4; ++nf) {
          int n = wc * 64 + nf * 16 + ll;
          int bs = lg ^ (n & 3);
          bv[nf] = *(const s8v*)&sB[cur][n * 32 + 8 * bs];
        }
        #pragma unroll
        for (int mf = 0; mf < 4; ++mf)
          #pragma unroll
          for (int nf = 0; nf < 4; ++nf)
            acc[mf][nf] = __builtin_amdgcn_mfma_f32_16x16x32_bf16(av[mf], bv[nf], acc[mf][nf], 0, 0, 0);
        // no second barrier needed: next write targets the other buffer; the
        // barrier above orders writes(s+1) after all reads(s-1) of that buffer.
      }
      // contract partial theta into per-lane msg registers
      #pragma unroll
      for (int mf = 0; mf < 4; ++mf)
        #pragma unroll
        for (int nf = 0; nf < 4; ++nf) {
          const int os = (FOUT == 32) ? (nf & 1) : nf;
          const int ii = (FOUT == 32) ? (nf >> 1) : 0;
          #pragma unroll
          for (int r = 0; r < 4; ++r)
            msgr[mf][r][os] += acc[mf][nf][r] * xsr[mf][r][ii];
        }
    }
  }

  // reduce msg registers across waves into LDS
  #pragma unroll
  for (int mf = 0; mf < 4; ++mf)
    #pragma unroll
    for (int r = 0; r < 4; ++r) {
      int row = wr * 64 + mf * 16 + (lg << 2) + r;
      #pragma unroll
      for (int os = 0; os < NOS; ++os)
        atomicAdd(&sMsg[row * FOUT + os * 16 + ll], msgr[mf][r][os]);
    }
  __syncthreads();

  // add theta-bias term (x_src @ reshape(bvec)) and scatter to agg[dst]
  for (int j = t; j < 128 * FOUT; j += 512) {
    int m = j / FOUT, o = j - m * FOUT;
    int d = sDst[m];
    if (d >= 0) {
      float v = sMsg[j];
      #pragma unroll
      for (int i = 0; i < 32; ++i) v = fmaf(sX[m * 32 + i], bvec[i * FOUT + o], v);
      atomicAdd(&agg[d * FOUT + o], v);
    }
  }
}

// ---------------- node update / pool / MLP ----------------

__global__ void k_node1(const float* __restrict__ x, const float* __restrict__ agg,
                        const int* __restrict__ cnt, const float* __restrict__ root,
                        const float* __restrict__ bias, float* __restrict__ h) {
  int tid = blockIdx.x * 256 + threadIdx.x;
  if (tid >= NV_N * 32) return;
  int n = tid >> 5, j = tid & 31;
  const float* xr = x + n * 32;
  float s = 0.f;
  #pragma unroll
  for (int i = 0; i < 32; ++i) s = fmaf(xr[i], root[i * 32 + j], s);
  int c = cnt[n]; if (c < 1) c = 1;
  h[tid] = fmaxf(agg[tid] / (float)c + s + bias[j], 0.f);
}

__global__ void k_node2(const float* __restrict__ hin, const float* __restrict__ agg,
                        const int* __restrict__ cnt, const float* __restrict__ root,
                        const float* __restrict__ bias, float* __restrict__ h2) {
  int tid = blockIdx.x * 256 + threadIdx.x;
  if (tid >= NV_N * 64) return;
  int n = tid >> 6, j = tid & 63;
  const float* xr = hin + n * 32;
  float s = 0.f;
  #pragma unroll
  for (int i = 0; i < 32; ++i) s = fmaf(xr[i], root[i * 64 + j], s);
  int c = cnt[n]; if (c < 1) c = 1;
  h2[tid] = fmaxf(agg[tid] / (float)c + s + bias[j], 0.f);
}

__device__ __forceinline__ int lowerb(const int* __restrict__ a, int n, int key) {
  int lo = 0, hi = n;
  while (lo < hi) { int mid = (lo + hi) >> 1; if (a[mid] < key) lo = mid + 1; else hi = mid; }
  return lo;
}

// one wave per graph; batch is sorted
__global__ void k_pool(const float* __restrict__ h2, const int* __restrict__ batch,
                       float* __restrict__ g) {
  int gid = (blockIdx.x * 256 + threadIdx.x) >> 6;
  int l = threadIdx.x & 63;
  if (gid >= NG_N) return;
  int lo = lowerb(batch, NV_N, gid);
  int hi = lowerb(batch, NV_N, gid + 1);
  float s = 0.f;
  for (int n = lo; n < hi; ++n) s += h2[n * 64 + l];
  int c = hi - lo; if (c < 1) c = 1;
  g[gid * 64 + l] = s / (float)c;
}

// fp32 MLP layer: out[r][n] = act(A[r]@W + bias), M=2000, N multiple of 256
template<int K, bool RELU>
__global__ void k_fc(const float* __restrict__ A, const float* __restrict__ W,
                     const float* __restrict__ bias, float* __restrict__ out, int N) {
  __shared__ float sA[8][K];
  int r0 = blockIdx.x * 8;
  int n = blockIdx.y * 256 + threadIdx.x;
  for (int j = threadIdx.x; j < 8 * K; j += 256) {
    int rr = j / K, kk = j - rr * K;
    int r = r0 + rr;
    sA[rr][kk] = (r < NG_N) ? A[r * K + kk] : 0.f;
  }
  __syncthreads();
  float acc[8] = {0.f, 0.f, 0.f, 0.f, 0.f, 0.f, 0.f, 0.f};
  for (int k = 0; k < K; ++k) {
    float b = W[k * N + n];
    #pragma unroll
    for (int rr = 0; rr < 8; ++rr) acc[rr] = fmaf(sA[rr][k], b, acc[rr]);
  }
  float bs = bias[n];
  #pragma unroll
  for (int rr = 0; rr < 8; ++rr) {
    int r = r0 + rr;
    if (r < NG_N) {
      float v = acc[rr] + bs;
      if (RELU) v = fmaxf(v, 0.f);
      out[r * N + n] = v;
    }
  }
}

__global__ void k_fc4(const float* __restrict__ A, const float* __restrict__ W,
                      const float* __restrict__ bias, float* __restrict__ out) {
  int tid = blockIdx.x * 256 + threadIdx.x;
  int r = tid >> 2, s = tid & 3;
  if (r >= NG_N || s >= 3) return;
  float acc = bias[s];
  for (int k = 0; k < 256; ++k) acc = fmaf(A[r * 256 + k], W[k * 3 + s], acc);
  out[r * 3 + s] = acc;
}

// ---------------- launch ----------------

extern "C" void kernel_launch(void* const* d_in, const int* in_sizes, int n_in,
                              void* d_out, int out_size, void* d_ws, size_t ws_size,
                              hipStream_t stream) {
  const float* x     = (const float*)d_in[0];
  const int*   ei    = (const int*)d_in[1];     // [2][E]
  const int*   eap   = (const int*)d_in[2];     // [E][2]
  const int*   batch = (const int*)d_in[3];
  const float* W1a   = (const float*)d_in[4];
  const float* b1a   = (const float*)d_in[5];
  const float* W1b   = (const float*)d_in[6];
  const float* b1b   = (const float*)d_in[7];
  const float* W2a   = (const float*)d_in[8];
  const float* b2a   = (const float*)d_in[9];
  const float* W2b   = (const float*)d_in[10];
  const float* b2b   = (const float*)d_in[11];
  const float* root1 = (const float*)d_in[12];
  const float* bias1 = (const float*)d_in[13];
  const float* root2 = (const float*)d_in[14];
  const float* bias2 = (const float*)d_in[15];
  const float* fcW1  = (const float*)d_in[16];
  const float* fcb1  = (const float*)d_in[17];
  const float* fcW2  = (const float*)d_in[18];
  const float* fcb2  = (const float*)d_in[19];
  const float* fcW3  = (const float*)d_in[20];
  const float* fcb3  = (const float*)d_in[21];
  const float* fcW4  = (const float*)d_in[22];
  const float* fcb4  = (const float*)d_in[23];
  float* out = (float*)d_out;

  char* w = (char*)d_ws;
  size_t off = 0;
  auto take = [&](size_t bytes) -> void* {
    void* p = w + off;
    off = (off + bytes + 255) & ~(size_t)255;
    return p;
  };
  unsigned short* tabs = (unsigned short*)take(4 * 256 * 1024 * 2);
  unsigned short* w1t  = (unsigned short*)take((size_t)1024 * 1024 * 2);
  unsigned short* w2t  = (unsigned short*)take((size_t)2048 * 1024 * 2);
  float* agg1 = (float*)take((size_t)NV_N * 32 * 4);
  float* agg2 = (float*)take((size_t)NV_N * 64 * 4);
  int*   cnt  = (int*)take((size_t)NV_N * 4);
  float* h    = (float*)take((size_t)NV_N * 32 * 4);
  float* h2   = (float*)take((size_t)NV_N * 64 * 4);
  float* g    = (float*)take((size_t)NG_N * 64 * 4);
  float* l1   = (float*)take((size_t)NG_N * 512 * 4);
  float* l2   = (float*)take((size_t)NG_N * 512 * 4);
  float* l3   = (float*)take((size_t)NG_N * 256 * 4);

  hipMemsetAsync(agg1, 0, (size_t)NV_N * 32 * 4, stream);
  hipMemsetAsync(agg2, 0, (size_t)NV_N * 64 * 4, stream);
  hipMemsetAsync(cnt, 0, (size_t)NV_N * 4, stream);

  k_tables<<<4096, 256, 0, stream>>>(W1a, b1a, W2a, b2a, tabs);
  k_transpose<<<(1024 / 32) * (1024 / 32), 256, 0, stream>>>(W1b, w1t, 1024, 1024);
  k_transpose<<<(1024 / 32) * (2048 / 32), 256, 0, stream>>>(W2b, w2t, 1024, 2048);
  k_count<<<(E_N + 255) / 256, 256, 0, stream>>>(ei, cnt);

  const int nblk = (E_N + 127) / 128;
  k_edge<1024, 32><<<nblk, 512, 0, stream>>>(x, ei, eap, tabs, tabs + 262144,
                                             w1t, b1b, agg1);
  k_node1<<<(NV_N * 32) / 256, 256, 0, stream>>>(x, agg1, cnt, root1, bias1, h);

  k_edge<2048, 64><<<nblk, 512, 0, stream>>>(h, ei, eap, tabs + 2 * 262144, tabs + 3 * 262144,
                                             w2t, b2b, agg2);
  k_node2<<<(NV_N * 64) / 256, 256, 0, stream>>>(h, agg2, cnt, root2, bias2, h2);

  k_pool<<<(NG_N * 64) / 256, 256, 0, stream>>>(h2, batch, g);

  k_fc<64, true><<<dim3((NG_N + 7) / 8, 2), 256, 0, stream>>>(g, fcW1, fcb1, l1, 512);
  k_fc<512, true><<<dim3((NG_N + 7) / 8, 2), 256, 0, stream>>>(l1, fcW2, fcb2, l2, 512);
  k_fc<512, true><<<dim3((NG_N + 7) / 8, 1), 256, 0, stream>>>(l2, fcW3, fcb3, l3, 256);
  k_fc4<<<(NG_N * 4 + 255) / 256, 256, 0, stream>>>(l3, fcW4, fcb4, out);
}